// Round 16
// baseline (163.973 us; speedup 1.0000x reference)
//
#include <hip/hip_runtime.h>
#include <math.h>

#define NA 8192
#define NE 32768
#define NT 256
#define NCH 33                 /* window chunks per i-block (coverage 4224 atoms) */
#define CHUNK 128              /* j-atoms per chunk */
#define IBLK 512               /* i-atoms per block (ITILE=2) */
#define NIB (NA / IBLK)        /* 16; steric grid = 16*33 = 528 */
#define NPAD 4352              /* spd sentinel padding: covers binStart+NCH*CHUNK */
#define NSLICE NCH             /* partial slices = 33 (4.1 MB) */

// ---- x-binning (key = pos.x ONLY; dD drift <=~0.02 A absorbed in margins) ----
#define NBIN 256
#define XMIN (-32.0f)
#define BW 0.25f
#define INVBW 4.0f
#define SKIPM 3.50f   /* chunk-skip margin: 2.88 real md + 2*BW + 0.08 drift + slack */
#define BSHIFT 13     /* window start: 13*0.25=3.25; gap 3.25-0.02-BW-0.04=2.94>2.88 */

// ---- workspace layout (4-byte element offsets) ----
#define WS_DEG      0                        // int NA
#define WS_BINCNT   (WS_DEG + NA)            // int NBIN
#define WS_DONE     (WS_BINCNT + NBIN)       // int NIB  (split-K done counters)
#define WS_GDONE    (WS_DONE + NIB)          // int 1
#define WS_MEMSET_N (WS_GDONE + 1)           // memset zeroes [0, here) ~ 34 KB
#define WS_LOSS     WS_MEMSET_N              // f32 4 (zeroed by k_deg)
#define WS_DD       (WS_LOSS + 4)            // f32 3NA (zeroed by k_deg)
#define WS_BINSTART (WS_DD + 3*NA)           // int NBIN (k_scatter block 0)
#define WS_IBBIN    (WS_BINSTART + NBIN)     // int NIB  (k_scatter block 0)
#define WS_BINOF    (WS_IBBIN + NIB)         // int NA: bin | (rank<<8)
#define WS_SPD      ((WS_BINOF + NA + 3) & ~3)   // float4 (NA+NPAD), sorted+sentinels
#define WS_SORIG    (WS_SPD + 4*(NA+NPAD))   // int NA, sorted->orig map
#define WS_PART     ((WS_SORIG + NA + 3) & ~3)   // float4 NSLICE*NA

// ---- chemistry tables (types present: {1,6,7,8,9,15,16,17}) ----
__device__ __forceinline__ float maxval_of(int z) {
    switch (z) {
        case 1: return 1.f; case 6: return 4.f; case 7: return 3.f; case 8: return 2.f;
        case 9: return 1.f; case 15: return 5.f; case 16: return 6.f; case 17: return 1.f;
        case 35: return 1.f; case 53: return 1.f; default: return 4.f;
    }
}
__device__ __forceinline__ float vdw_of(int z) {
    switch (z) {
        case 1: return 1.2f; case 6: return 1.7f; case 7: return 1.55f; case 8: return 1.52f;
        case 9: return 1.47f; case 15: return 1.8f; case 16: return 1.8f; case 17: return 1.75f;
        case 35: return 1.85f; case 53: return 1.98f; default: return 1.6f;
    }
}
__device__ __forceinline__ float bond_of(int a, int b) {
    int lo = a < b ? a : b, hi = a < b ? b : a;
    switch (lo * 64 + hi) {
        case 6*64+6:   return 1.54f;
        case 6*64+7:   return 1.47f;
        case 6*64+8:   return 1.43f;
        case 6*64+16:  return 1.82f;
        case 6*64+9:   return 1.35f;
        case 6*64+17:  return 1.77f;
        case 1*64+6:   return 1.09f;
        case 7*64+7:   return 1.45f;
        case 7*64+8:   return 1.40f;
        case 1*64+7:   return 1.01f;
        case 8*64+8:   return 1.48f;
        case 1*64+8:   return 0.96f;
        case 16*64+16: return 2.05f;
        case 8*64+15:  return 1.63f;
        default:       return 1.5f;
    }
}
__device__ __forceinline__ float viol_of(int d, int z) {
    return fmaxf((float)d - maxval_of(z), 0.f);
}
__device__ __forceinline__ int bin_of_x(float x) {
    int b = (int)floorf((x - XMIN) * INVBW);
    return min(max(b, 0), NBIN - 1);
}

__device__ __forceinline__ float wave_reduce_sum(float x) {
    #pragma unroll
    for (int off = 32; off > 0; off >>= 1) x += __shfl_down(x, off);
    return x;  // valid in lane 0 of each wave
}

// ---- 1. deg histogram + x-bin histogram (pos-only key) + zero loss/dD + sentinels
__global__ void k_deg(const int* __restrict__ row, const float* __restrict__ pos,
                      int* __restrict__ deg, int* __restrict__ binCnt,
                      int* __restrict__ binOf, float4* __restrict__ spd,
                      float* __restrict__ zbase /* = ws_f + WS_LOSS */) {
    int e = blockIdx.x * NT + threadIdx.x;
    if (e < 3 * NA + 4) zbase[e] = 0.f;     // zeroes lossAcc[4] + dD[3*NA]
    if (e < NPAD) spd[NA + e] = make_float4(1e9f, 1e9f, 1e9f, 0.f);  // sentinels
    if (e < NA) {                            // bin by pos.x (dD not yet known)
        int b = bin_of_x(pos[3*e]);
        int rank = atomicAdd(&binCnt[b], 1); // rank-at-pack: scatter atomic-free
        binOf[e] = b | (rank << 8);          // b<256, rank<8192
    }
    if (e < NE) atomicAdd(&deg[row[e]], 1);
}

// ---- 2. fused bond + valence push + both losses (proven round-0 form) ----
__global__ void k_edge(const int* __restrict__ row, const int* __restrict__ col,
                       const int* __restrict__ types, const int* __restrict__ deg,
                       const float* __restrict__ pos, float* __restrict__ dD,
                       float* __restrict__ lossAcc) {
    int e = blockIdx.x * NT + threadIdx.x;
    float l1 = 0.f, l0 = 0.f;
    if (e < NE) {
        int r = row[e], c = col[e];
        float bx = pos[3*r]   - pos[3*c];
        float by = pos[3*r+1] - pos[3*c+1];
        float bz = pos[3*r+2] - pos[3*c+2];
        float cur = sqrtf(bx*bx + by*by + bz*bz);
        float tgt = bond_of(types[r], types[c]);
        float diff = cur - tgt;
        l1 = diff * diff;
        float ratio = tgt / (cur + 1e-8f);
        ratio = fminf(fmaxf(ratio, 0.98f), 1.02f);
        float s = (ratio - 1.f) * 0.01f * 0.5f;
        float v = viol_of(deg[r], types[r]);
        float sc = (v > 0.f) ? (v * 1e-3f / (cur + 1e-8f)) : 0.f;
        float rs = s + sc;
        atomicAdd(&dD[3*r],   bx * rs);
        atomicAdd(&dD[3*r+1], by * rs);
        atomicAdd(&dD[3*r+2], bz * rs);
        atomicAdd(&dD[3*c],   -bx * s);
        atomicAdd(&dD[3*c+1], -by * s);
        atomicAdd(&dD[3*c+2], -bz * s);
    }
    if (e < NA) {                              // valence loss (deg complete here)
        float v = viol_of(deg[e], types[e]);
        l0 = v * v;
    }
    float p1 = wave_reduce_sum(l1);
    float p0 = wave_reduce_sum(l0);
    if ((threadIdx.x & 63) == 0) {
        if (p1 != 0.f) atomicAdd(&lossAcc[1], p1);
        if (p0 != 0.f) atomicAdd(&lossAcc[0], p0);
    }
}

// ---- 3. counting-sort scatter (atomic-free) + inline pack + ibBin precompute ----
__global__ void k_scatter(const float* __restrict__ pos, const float* __restrict__ dD,
                          const int* __restrict__ types, const int* __restrict__ binOf,
                          const int* __restrict__ binCnt, int* __restrict__ binStartG,
                          int* __restrict__ ibBinG,
                          float4* __restrict__ spd, int* __restrict__ sorig) {
    __shared__ int buf[NBIN];
    __shared__ int sStart[NBIN];
    const int t = threadIdx.x;          // NT == NBIN == 256
    buf[t] = binCnt[t];
    __syncthreads();
    int own = buf[t];
    for (int off = 1; off < NBIN; off <<= 1) {   // Hillis-Steele inclusive scan
        int v = (t >= off) ? buf[t - off] : 0;
        __syncthreads();
        buf[t] += v;
        __syncthreads();
    }
    sStart[t] = buf[t] - own;                    // exclusive prefix
    if (blockIdx.x == 0) binStartG[t] = sStart[t];
    __syncthreads();
    // exact pos-bin of each i-block's first sorted slot (kills the bin(stored)
    // vs bin(pos) off-by-one hazard in the window-start derivation)
    if (blockIdx.x == 0 && t < NIB) {
        int S = t * IBLK;
        int lo = 0, hi = NBIN;                   // first bin with sStart > S
        while (lo < hi) { int mid = (lo + hi) >> 1;
                          if (sStart[mid] <= S) lo = mid + 1; else hi = mid; }
        ibBinG[t] = lo - 1;                      // owner bin of slot S
    }
    int a = blockIdx.x * NT + t;
    int v = binOf[a];
    int dst = sStart[v & 255] + (v >> 8);
    spd[dst] = make_float4(pos[3*a]   + dD[3*a],
                           pos[3*a+1] + dD[3*a+1],
                           pos[3*a+2] + dD[3*a+2],
                           vdw_of(types[a]) * 0.8f);
    sorig[dst] = a;
}

// branchless steric pair (round-0 proven form)
__device__ __forceinline__ void steric_pair(const float4 p, const float4 q,
                                            float& cs, float& sx, float& sy, float& sz,
                                            float& ll) {
    float dx = p.x - q.x, dy = p.y - q.y, dz = p.z - q.z;
    float d2 = fmaf(dx, dx, fmaf(dy, dy, dz * dz));
    float md = p.w + q.w;
    float rinv = rsqrtf(fmaxf(d2, 1e-12f));
    float dist = d2 * rinv;                 // sqrt(d2)
    float t1 = md - dist;
    bool ok = (t1 > 0.f) && (d2 > 1e-12f);  // d2 gate = diagonal (i==j)
    float t1c = ok ? t1 : 0.f;
    ll = fmaf(t1c, t1c, ll);
    float co = t1c * rinv;
    cs += co;
    sx = fmaf(co, q.x, sx);
    sy = fmaf(co, q.y, sy);
    sz = fmaf(co, q.z, sz);
}

// ---- 4. steric + FUSED split-K reduce (last chunk-block per i-block reduces) --
// Chunk/window culling margins: see R13/R15 derivation (unchanged, proven).
// Fusion protocol (G16-safe): every chunk block (skip path included) writes its
// partials, then __threadfence() [device-scope release: partials + lossAcc
// visible across XCDs], then t0 does atomicAdd(done[ib]).  The block seeing
// old==NCH-1 reduces all 33 slices for its 512 atoms and writes out[] via
// sorig.  A second counter gdone serializes the loss scalar after ALL 16
// reductions (transitively after every lossAcc contribution).  done/gdone live
// in the memset range (harness re-poisons ws between iterations).
__global__ void __launch_bounds__(NT)
k_steric(const float4* __restrict__ spd, const int* __restrict__ binStart,
         const int* __restrict__ ibBin, const int* __restrict__ sorig,
         float4* __restrict__ partial, float* __restrict__ lossAcc,
         int* __restrict__ done, int* __restrict__ gdone,
         float* __restrict__ out) {
    __shared__ float4 sm[CHUNK];
    __shared__ int isLast;
    const int t = threadIdx.x;
    const int b = blockIdx.x;
    const int ib = b / NCH;                // [0,16) i-block of 512 sorted atoms
    const int c  = b % NCH;                // [0,33) window chunk
    const int i0 = ib * IBLK + t;
    const int i1 = i0 + NT;
    float xlo = spd[ib * IBLK].x;              // +-(BW+0.04) estimates
    float xhi = spd[ib * IBLK + IBLK - 1].x;
    int bs = ibBin[ib] - BSHIFT; bs = bs < 0 ? 0 : bs;
    const int jbase = binStart[bs] + c * CHUNK;   // <= 8191+4224 < NA+NPAD
    // block-uniform skip decision (no early return: done-protocol must run)
    bool skip = (spd[jbase].x > xhi + SKIPM) ||
                (spd[jbase + CHUNK - 1].x < xlo - SKIPM);
    if (skip) {
        float4 z = make_float4(0.f, 0.f, 0.f, 0.f);
        partial[c * NA + i0] = z;
        partial[c * NA + i1] = z;
    } else {
        if (t < CHUNK) sm[t] = spd[jbase + t];
        float4 p0 = spd[i0];
        float4 p1 = spd[i1];
        __syncthreads();
        float cs0 = 0.f, sx0 = 0.f, sy0 = 0.f, sz0 = 0.f, ll0 = 0.f;
        float cs1 = 0.f, sx1 = 0.f, sy1 = 0.f, sz1 = 0.f, ll1 = 0.f;
        #pragma unroll 8
        for (int jj = 0; jj < CHUNK; jj++) {
            float4 q = sm[jj];
            steric_pair(p0, q, cs0, sx0, sy0, sz0, ll0);
            steric_pair(p1, q, cs1, sx1, sy1, sz1, ll1);
        }
        partial[c * NA + i0] = make_float4(cs0, sx0, sy0, sz0);
        partial[c * NA + i1] = make_float4(cs1, sx1, sy1, sz1);
        float part = wave_reduce_sum(ll0 + ll1);
        if ((t & 63) == 0 && part != 0.f) atomicAdd(&lossAcc[2], part);
    }
    // ---- split-K completion protocol ----
    __threadfence();                       // release: partials + loss visible
    if (t == 0) {
        int old = atomicAdd(&done[ib], 1);
        isLast = (old == NCH - 1) ? 1 : 0;
    }
    __syncthreads();
    if (!isLast) return;
    // ---- fused reduce for this i-block (512 atoms, 2 per thread) ----
    #pragma unroll
    for (int k = 0; k < 2; k++) {
        int s = ib * IBLK + k * NT + t;
        float cs = 0.f, sx = 0.f, sy = 0.f, sz = 0.f;
        #pragma unroll 3
        for (int y = 0; y < NSLICE; y++) {
            float4 u = partial[y * NA + s];
            cs += u.x; sx += u.y; sy += u.z; sz += u.w;
        }
        float4 p = spd[s];
        float cf = 1.f + cs * 0.0025f;
        int orig = sorig[s];
        out[3*orig]   = p.x * cf - sx * 0.0025f;
        out[3*orig+1] = p.y * cf - sy * 0.0025f;
        out[3*orig+2] = p.z * cf - sz * 0.0025f;
    }
    __syncthreads();
    if (t == 0) {
        __threadfence();
        int g = atomicAdd(gdone, 1);
        if (g == NIB - 1) {                // after ALL reductions => all lossAcc
            float loss = lossAcc[0] + lossAcc[1] * (1.f / NE) + lossAcc[2] * 0.5f;
            out[3*NA] = loss * 0.1f;
        }
    }
}

extern "C" void kernel_launch(void* const* d_in, const int* in_sizes, int n_in,
                              void* d_out, int out_size, void* d_ws, size_t ws_size,
                              hipStream_t stream) {
    (void)in_sizes; (void)n_in; (void)out_size; (void)ws_size;
    const float* pos   = (const float*)d_in[0];
    const int*   eidx  = (const int*)d_in[1];
    const int*   types = (const int*)d_in[2];
    const int* row = eidx;
    const int* col = eidx + NE;

    int*   ws_i = (int*)d_ws;
    float* ws_f = (float*)d_ws;
    int*    deg      = ws_i + WS_DEG;
    int*    binCnt   = ws_i + WS_BINCNT;
    int*    done     = ws_i + WS_DONE;
    int*    gdone    = ws_i + WS_GDONE;
    float*  lossAcc  = ws_f + WS_LOSS;
    float*  dD       = ws_f + WS_DD;
    int*    binStart = ws_i + WS_BINSTART;
    int*    ibBin    = ws_i + WS_IBBIN;
    int*    binOf    = ws_i + WS_BINOF;
    float4* spd      = (float4*)(ws_f + WS_SPD);
    int*    sorig    = ws_i + WS_SORIG;
    float4* partial  = (float4*)(ws_f + WS_PART);
    float*  out      = (float*)d_out;

    hipMemsetAsync(d_ws, 0, (size_t)WS_MEMSET_N * 4, stream);  // deg+bin+done
    k_deg    <<<NE/NT, NT, 0, stream>>>(row, pos, deg, binCnt, binOf, spd,
                                        ws_f + WS_LOSS);
    k_edge   <<<NE/NT, NT, 0, stream>>>(row, col, types, deg, pos, dD, lossAcc);
    k_scatter<<<NA/NT, NT, 0, stream>>>(pos, dD, types, binOf, binCnt,
                                        binStart, ibBin, spd, sorig);
    k_steric <<<NIB*NCH, NT, 0, stream>>>(spd, binStart, ibBin, sorig,
                                          partial, lossAcc, done, gdone, out);
}

// Round 17
// 127.434 us; speedup vs baseline: 1.2867x; 1.2867x over previous
//
#include <hip/hip_runtime.h>
#include <math.h>

#define NA 8192
#define NE 32768
#define NT 256
#define NCH 32                 /* window chunks per i-block */
#define CHUNK 128              /* j-atoms per chunk; window bound = 4096 */
#define IBLK 512               /* i-atoms per block (ITILE=2) */
#define NIB (NA / IBLK)        /* 16; steric grid = 16*32 = 512 = 2 blocks/CU */
#define NPAD 4096              /* spd sentinel padding */
#define NSLICE NCH             /* partial slices = 32 (4 MB) */

// ---- x-binning for exact steric culling ----
#define NBIN 256
#define XMIN (-32.0f)
#define BW 0.25f
#define INVBW 4.0f
#define MDMAX 3.168f           /* conservative md bound used for window start */
#define SKIPM 3.40f            /* chunk-skip margin: real md<=2.88 + 2*BW + slack */
#define BSHIFT 13              /* 13 bins * 0.25 = 3.25 >= MDMAX: window start sound */

// ---- workspace layout (4-byte element offsets) ----
#define WS_DEG      0                        // int NA
#define WS_BINCNT   (WS_DEG + NA)            // int NBIN
#define WS_MEMSET_N (WS_BINCNT + NBIN)       // memset zeroes [0, here)
#define WS_LOSS     WS_MEMSET_N              // f32 4 (zeroed by k_deg)
#define WS_DD       (WS_LOSS + 4)            // f32 3NA (zeroed by k_deg)
#define WS_BINSTART (WS_DD + 3*NA)           // int NBIN (written by k_scatter)
#define WS_BINOF    (WS_BINSTART + NBIN)     // int NA: bin | (rank<<8)
#define WS_PD       ((WS_BINOF + NA + 3) & ~3)   // float4 NA (16B aligned)
#define WS_SPD      (WS_PD + 4*NA)           // float4 (NA+NPAD), sorted+sentinels
#define WS_SORIG    (WS_SPD + 4*(NA+NPAD))   // int NA, sorted->orig map
#define WS_PART     ((WS_SORIG + NA + 3) & ~3)   // float4 NSLICE*NA = 4 MB

// ---- chemistry tables (types present: {1,6,7,8,9,15,16,17}) ----
__device__ __forceinline__ float maxval_of(int z) {
    switch (z) {
        case 1: return 1.f; case 6: return 4.f; case 7: return 3.f; case 8: return 2.f;
        case 9: return 1.f; case 15: return 5.f; case 16: return 6.f; case 17: return 1.f;
        case 35: return 1.f; case 53: return 1.f; default: return 4.f;
    }
}
__device__ __forceinline__ float vdw_of(int z) {
    switch (z) {
        case 1: return 1.2f; case 6: return 1.7f; case 7: return 1.55f; case 8: return 1.52f;
        case 9: return 1.47f; case 15: return 1.8f; case 16: return 1.8f; case 17: return 1.75f;
        case 35: return 1.85f; case 53: return 1.98f; default: return 1.6f;
    }
}
__device__ __forceinline__ float bond_of(int a, int b) {
    int lo = a < b ? a : b, hi = a < b ? b : a;
    switch (lo * 64 + hi) {
        case 6*64+6:   return 1.54f;
        case 6*64+7:   return 1.47f;
        case 6*64+8:   return 1.43f;
        case 6*64+16:  return 1.82f;
        case 6*64+9:   return 1.35f;
        case 6*64+17:  return 1.77f;
        case 1*64+6:   return 1.09f;
        case 7*64+7:   return 1.45f;
        case 7*64+8:   return 1.40f;
        case 1*64+7:   return 1.01f;
        case 8*64+8:   return 1.48f;
        case 1*64+8:   return 0.96f;
        case 16*64+16: return 2.05f;
        case 8*64+15:  return 1.63f;
        default:       return 1.5f;
    }
}
__device__ __forceinline__ float viol_of(int d, int z) {
    return fmaxf((float)d - maxval_of(z), 0.f);
}
__device__ __forceinline__ int bin_of_x(float x) {
    int b = (int)floorf((x - XMIN) * INVBW);
    return min(max(b, 0), NBIN - 1);
}

__device__ __forceinline__ float wave_reduce_sum(float x) {
    #pragma unroll
    for (int off = 32; off > 0; off >>= 1) x += __shfl_down(x, off);
    return x;  // valid in lane 0 of each wave
}

// ---- 1. out-degree histogram + zero loss/dD (spare range, disjoint from deg) ----
__global__ void k_deg(const int* __restrict__ row, int* __restrict__ deg,
                      float* __restrict__ zbase /* = ws_f + WS_LOSS */) {
    int e = blockIdx.x * NT + threadIdx.x;
    if (e < 3 * NA + 4) zbase[e] = 0.f;     // zeroes lossAcc[4] + dD[3*NA]
    if (e < NE) atomicAdd(&deg[row[e]], 1);
}

// ---- 2. fused bond + valence push + both losses (proven round-0 form) ----
__global__ void k_edge(const int* __restrict__ row, const int* __restrict__ col,
                       const int* __restrict__ types, const int* __restrict__ deg,
                       const float* __restrict__ pos, float* __restrict__ dD,
                       float* __restrict__ lossAcc) {
    int e = blockIdx.x * NT + threadIdx.x;
    float l1 = 0.f, l0 = 0.f;
    if (e < NE) {
        int r = row[e], c = col[e];
        float bx = pos[3*r]   - pos[3*c];
        float by = pos[3*r+1] - pos[3*c+1];
        float bz = pos[3*r+2] - pos[3*c+2];
        float cur = sqrtf(bx*bx + by*by + bz*bz);
        float tgt = bond_of(types[r], types[c]);
        float diff = cur - tgt;
        l1 = diff * diff;
        float ratio = tgt / (cur + 1e-8f);
        ratio = fminf(fmaxf(ratio, 0.98f), 1.02f);
        float s = (ratio - 1.f) * 0.01f * 0.5f;
        float v = viol_of(deg[r], types[r]);
        float sc = (v > 0.f) ? (v * 1e-3f / (cur + 1e-8f)) : 0.f;
        float rs = s + sc;
        atomicAdd(&dD[3*r],   bx * rs);
        atomicAdd(&dD[3*r+1], by * rs);
        atomicAdd(&dD[3*r+2], bz * rs);
        atomicAdd(&dD[3*c],   -bx * s);
        atomicAdd(&dD[3*c+1], -by * s);
        atomicAdd(&dD[3*c+2], -bz * s);
    }
    if (e < NA) {                              // valence loss (deg complete here)
        float v = viol_of(deg[e], types[e]);
        l0 = v * v;
    }
    float p1 = wave_reduce_sum(l1);
    float p0 = wave_reduce_sum(l0);
    if ((threadIdx.x & 63) == 0) {
        if (p1 != 0.f) atomicAdd(&lossAcc[1], p1);
        if (p0 != 0.f) atomicAdd(&lossAcc[0], p0);
    }
}

// ---- 2.5 pack (pos+dD, vdw*0.8) + x-bin histogram (rank kept!) + sentinels ----
__global__ void k_pack(const float* __restrict__ pos, const float* __restrict__ dD,
                       const int* __restrict__ types, float4* __restrict__ pd,
                       float4* __restrict__ spd, int* __restrict__ binOf,
                       int* __restrict__ binCnt) {
    int a = blockIdx.x * NT + threadIdx.x;
    float4 v = make_float4(pos[3*a]   + dD[3*a],
                           pos[3*a+1] + dD[3*a+1],
                           pos[3*a+2] + dD[3*a+2],
                           vdw_of(types[a]) * 0.8f);
    pd[a] = v;
    int b = bin_of_x(v.x);
    int rank = atomicAdd(&binCnt[b], 1);     // rank-at-pack: scatter needs no atomics
    binOf[a] = b | (rank << 8);              // b<256, rank<8192 -> fits 21 bits
    // sentinel pad: far atoms contribute exactly 0 through the branchless pair
    if (a < NPAD) spd[NA + a] = make_float4(1e9f, 1e9f, 1e9f, 0.f);
}

// ---- 2.75 counting-sort scatter (atomic-free; redundant 256-bin LDS scan) ----
__global__ void k_scatter(const float4* __restrict__ pd, const int* __restrict__ binOf,
                          const int* __restrict__ binCnt, int* __restrict__ binStartG,
                          float4* __restrict__ spd, int* __restrict__ sorig) {
    __shared__ int buf[NBIN];
    const int t = threadIdx.x;          // NT == NBIN == 256
    buf[t] = binCnt[t];
    __syncthreads();
    int own = buf[t];
    for (int off = 1; off < NBIN; off <<= 1) {   // Hillis-Steele inclusive scan
        int v = (t >= off) ? buf[t - off] : 0;
        __syncthreads();
        buf[t] += v;
        __syncthreads();
    }
    __shared__ int sStart[NBIN];
    sStart[t] = buf[t] - own;                    // exclusive prefix
    if (blockIdx.x == 0) binStartG[t] = buf[t] - own;
    __syncthreads();
    int a = blockIdx.x * NT + t;
    int v = binOf[a];
    int dst = sStart[v & 255] + (v >> 8);
    spd[dst] = pd[a];
    sorig[dst] = a;
}

// branchless steric pair (round-0 proven form)
__device__ __forceinline__ void steric_pair(const float4 p, const float4 q,
                                            float& cs, float& sx, float& sy, float& sz,
                                            float& ll) {
    float dx = p.x - q.x, dy = p.y - q.y, dz = p.z - q.z;
    float d2 = fmaf(dx, dx, fmaf(dy, dy, dz * dz));
    float md = p.w + q.w;
    float rinv = rsqrtf(fmaxf(d2, 1e-12f));
    float dist = d2 * rinv;                 // sqrt(d2)
    float t1 = md - dist;
    bool ok = (t1 > 0.f) && (d2 > 1e-12f);  // d2 gate = diagonal (i==j)
    float t1c = ok ? t1 : 0.f;
    ll = fmaf(t1c, t1c, ll);
    float co = t1c * rinv;
    cs += co;
    sx = fmaf(co, q.x, sx);
    sy = fmaf(co, q.y, sy);
    sz = fmaf(co, q.z, sz);
}

// ---- 3. steric over x-SORTED atoms: contiguous-window chunks, BRANCHLESS loop ----
// Window start (binStart[bin(xlo)-13]) is sound: excluded atoms have
// x < edge(bin(xlo)) - 3.25 <= xlo_true - 3.25 < xlo_true - md.  Chunk skips
// tolerate WITHIN-BIN DISORDER (slot-range endpoints bound true min/max to
// +-BW): skip-above iff spd[jbase].x > xhi + 2.88 + 2*BW; skip-below iff
// spd[jbase+CHUNK-1].x < xlo - 2.88 - 2*BW.  SKIPM=3.40 covers both.
__global__ void __launch_bounds__(NT)
k_steric(const float4* __restrict__ spd, const int* __restrict__ binStart,
         float4* __restrict__ partial, float* __restrict__ lossAcc) {
    __shared__ float4 sm[CHUNK];
    const int t = threadIdx.x;
    const int b = blockIdx.x;
    const int ib = b >> 5;                 // [0,16) i-block of 512 sorted atoms
    const int c  = b & 31;                 // [0,32) window chunk
    const int i0 = ib * IBLK + t;
    const int i1 = i0 + NT;
    float xlo = spd[ib * IBLK].x;              // +-BW estimates (bin disorder)
    float xhi = spd[ib * IBLK + IBLK - 1].x;
    int bs = bin_of_x(xlo) - BSHIFT; bs = bs < 0 ? 0 : bs;
    const int jbase = binStart[bs] + c * CHUNK;   // <= 8191 + 3968; reads < NA+NPAD
    if (spd[jbase].x > xhi + SKIPM || spd[jbase + CHUNK - 1].x < xlo - SKIPM) {
        float4 z = make_float4(0.f, 0.f, 0.f, 0.f);
        partial[c * NA + i0] = z;
        partial[c * NA + i1] = z;
        return;                            // block-uniform: no barrier issues
    }
    if (t < CHUNK) sm[t] = spd[jbase + t];
    float4 p0 = spd[i0];
    float4 p1 = spd[i1];
    __syncthreads();
    float cs0 = 0.f, sx0 = 0.f, sy0 = 0.f, sz0 = 0.f, ll0 = 0.f;
    float cs1 = 0.f, sx1 = 0.f, sy1 = 0.f, sz1 = 0.f, ll1 = 0.f;
    #pragma unroll 8
    for (int jj = 0; jj < CHUNK; jj++) {
        float4 q = sm[jj];
        steric_pair(p0, q, cs0, sx0, sy0, sz0, ll0);
        steric_pair(p1, q, cs1, sx1, sy1, sz1, ll1);
    }
    partial[c * NA + i0] = make_float4(cs0, sx0, sy0, sz0);
    partial[c * NA + i1] = make_float4(cs1, sx1, sy1, sz1);
    float part = wave_reduce_sum(ll0 + ll1);
    if ((t & 63) == 0 && part != 0.f) atomicAdd(&lossAcc[2], part);
}

// ---- 4. reduce 32 slices per sorted atom + scatter final output via sorig ----
__global__ void k_reduce(const float4* __restrict__ spd, const int* __restrict__ sorig,
                         const float4* __restrict__ partial,
                         const float* __restrict__ lossAcc, float* __restrict__ out) {
    int s = blockIdx.x * NT + threadIdx.x;   // sorted position
    float cs = 0.f, sx = 0.f, sy = 0.f, sz = 0.f;
    #pragma unroll 8
    for (int y = 0; y < NSLICE; y++) {
        float4 u = partial[y * NA + s];      // coalesced: consecutive s per lane
        cs += u.x; sx += u.y; sy += u.z; sz += u.w;
    }
    float4 p = spd[s];
    float c = 1.f + cs * 0.0025f;
    int orig = sorig[s];
    out[3*orig]   = p.x * c - sx * 0.0025f;
    out[3*orig+1] = p.y * c - sy * 0.0025f;
    out[3*orig+2] = p.z * c - sz * 0.0025f;
    if (s == 0) {
        float loss = lossAcc[0] + lossAcc[1] * (1.f / NE) + lossAcc[2] * 0.5f;
        out[3*NA] = loss * 0.1f;
    }
}

extern "C" void kernel_launch(void* const* d_in, const int* in_sizes, int n_in,
                              void* d_out, int out_size, void* d_ws, size_t ws_size,
                              hipStream_t stream) {
    (void)in_sizes; (void)n_in; (void)out_size; (void)ws_size;
    const float* pos   = (const float*)d_in[0];
    const int*   eidx  = (const int*)d_in[1];
    const int*   types = (const int*)d_in[2];
    const int* row = eidx;
    const int* col = eidx + NE;

    int*   ws_i = (int*)d_ws;
    float* ws_f = (float*)d_ws;
    int*    deg      = ws_i + WS_DEG;
    int*    binCnt   = ws_i + WS_BINCNT;
    float*  lossAcc  = ws_f + WS_LOSS;
    float*  dD       = ws_f + WS_DD;
    int*    binStart = ws_i + WS_BINSTART;
    int*    binOf    = ws_i + WS_BINOF;
    float4* pd       = (float4*)(ws_f + WS_PD);
    float4* spd      = (float4*)(ws_f + WS_SPD);
    int*    sorig    = ws_i + WS_SORIG;
    float4* partial  = (float4*)(ws_f + WS_PART);
    float*  out      = (float*)d_out;

    hipMemsetAsync(d_ws, 0, (size_t)WS_MEMSET_N * 4, stream);  // deg + binCnt
    k_deg    <<<NE/NT, NT, 0, stream>>>(row, deg, ws_f + WS_LOSS);
    k_edge   <<<NE/NT, NT, 0, stream>>>(row, col, types, deg, pos, dD, lossAcc);
    k_pack   <<<NA/NT, NT, 0, stream>>>(pos, dD, types, pd, spd, binOf, binCnt);
    k_scatter<<<NA/NT, NT, 0, stream>>>(pd, binOf, binCnt, binStart, spd, sorig);
    k_steric <<<NIB*NCH, NT, 0, stream>>>(spd, binStart, partial, lossAcc);
    k_reduce <<<NA/NT, NT, 0, stream>>>(spd, sorig, partial, lossAcc, out);
}